// Round 16
// baseline (56.118 us; speedup 1.0000x reference)
//
#include <hip/hip_runtime.h>
#include <hip/hip_bf16.h>

typedef __attribute__((ext_vector_type(4))) float f32x4;
typedef __attribute__((ext_vector_type(8))) short bf16x8;

#define N_NEI 64
#define D_IN  128
#define D_HID 128

union BF8 { bf16x8 v; __hip_bfloat162 h[4]; unsigned u[4]; };

__device__ __forceinline__ unsigned bfbits(float f) {
  unsigned u = __float_as_uint(f);
  return (u + 0x7fffu + ((u >> 16) & 1u)) >> 16;  // RNE fp32->bf16
}

__device__ __forceinline__ bf16x8 pack8(const float4& a, const float4& b) {
  BF8 r;
  r.h[0] = __float22bfloat162_rn(float2{a.x, a.y});
  r.h[1] = __float22bfloat162_rn(float2{a.z, a.w});
  r.h[2] = __float22bfloat162_rn(float2{b.x, b.y});
  r.h[3] = __float22bfloat162_rn(float2{b.z, b.w});
  return r.v;
}

// Kernel 1 (wave-private DMA pipeline — R12 repaired):
//   pooled[b][j] = max_n relu(neigh[b,n,:]·W_mlp[j,:] + b_mlp[j]), masked n -> 0.
// Diagnosis chain: R8's VGPR A-path caps in-flight bytes (45% HBM duty; every
// reg-cap spills). R12's DMA fix failed on (a) WRONG PAD: 32B pad -> 4-way bank
// conflict, 25.7M cycles; (b) 4x cross-wave LDS redundancy. Repairs here:
//   - 16B pad per 1KB chunk: read span = (chunk + 2*lg) mod 8 -> all 8 spans,
//     2-way minimum (m136: ~free)
//   - wave-private tiles: each wave owns 4 batch rows + its own LDS dbuf ->
//     zero redundancy, ZERO loop barriers
//   - A staged via global_load_lds: zero VGPRs in flight -> register wall gone
//   - grid 256 = 1 block/CU exactly; wave streams 128KB linearly, 8KB/step,
//     depth-1 DMA prefetch; per-CU in-flight ~32KB >> 9.2KB Little's-law need
__global__ __launch_bounds__(256, 1)
void k1_pool(const float* __restrict__ neigh, const float* __restrict__ Wmlp,
             const float* __restrict__ bmlp, unsigned short* __restrict__ pooled) {
  __shared__ unsigned short Wl[D_HID * D_IN];            // 32KB bf16, swizzled
  __shared__ __align__(16) char Abuf[4][2][8 * 1040];    // 4 waves x dbuf x (8KB + 8x16B pad)
  __shared__ float pscr[4][D_HID];                       // per-wave epilogue scratch

  const int tid = threadIdx.x;
  const int l = tid & 63;
  const int w = tid >> 6;
  const int lr = l & 15;   // A row-in-tile / B col-in-tile
  const int lg = l >> 4;   // k-group

  const int brow0 = blockIdx.x * 16 + w * 4;   // this wave's 4 batch rows
  const char* wsrc = (const char*)(neigh + (size_t)brow0 * N_NEI * D_IN);  // 128KB, linear

  // DMA step 0 (8 x 1KB chunks) — flies under W staging
  #pragma unroll
  for (int i = 0; i < 8; ++i) {
    __builtin_amdgcn_global_load_lds(
      (const __attribute__((address_space(1))) unsigned int*)(wsrc + i * 1024 + l * 16),
      (__attribute__((address_space(3))) unsigned int*)(&Abuf[w][0][0] + i * 1040),
      16, 0, 0);
  }

  // stage W_mlp -> LDS bf16 (swizzled: byte = j*256 + ((d*2) ^ ((j&7)<<4)))
  const float4* W4 = (const float4*)Wmlp;
  #pragma unroll
  for (int it = 0; it < 8; ++it) {
    int f8 = it * 256 + tid;            // 8-float chunk id, 0..2047
    int j  = f8 >> 4;                   // row 0..127
    int d0 = (f8 & 15) * 8;             // col start
    float4 a = W4[f8 * 2];
    float4 bb = W4[f8 * 2 + 1];
    int byte = j * 256 + ((d0 * 2) ^ ((j & 7) << 4));
    *(bf16x8*)((char*)Wl + byte) = pack8(a, bb);
  }

  float bml[8];
  #pragma unroll
  for (int t = 0; t < 8; ++t) bml[t] = bmlp[t * 16 + lr];

  __syncthreads();   // W visible to all waves; also drains DMA(0). ONLY barrier.

  float pmax[8];
  #pragma unroll
  for (int t = 0; t < 8; ++t) pmax[t] = 0.f;  // exact: masked rows are 0, relu >= 0

  #pragma unroll 1
  for (int s = 0; s < 16; ++s) {        // 4 rows x 4 tiles of 16 neighbors; src = wsrc + s*8KB
    // 1. issue DMA for step s+1 into the other buffer (zero VGPR in flight)
    if (s < 15) {
      const char* src = wsrc + (size_t)(s + 1) * 8192;
      char* dst = &Abuf[w][(s + 1) & 1][0];
      #pragma unroll
      for (int i = 0; i < 8; ++i) {
        __builtin_amdgcn_global_load_lds(
          (const __attribute__((address_space(1))) unsigned int*)(src + i * 1024 + l * 16),
          (__attribute__((address_space(3))) unsigned int*)(dst + i * 1040),
          16, 0, 0);
      }
    }

    // 2. A fragments from own LDS tile (fp32 -> bf16) + exact fp32 row-sum
    const char* Ab = &Abuf[w][s & 1][0];
    bf16x8 af[4];
    float rs = 0.f;
    #pragma unroll
    for (int ks = 0; ks < 4; ++ks) {
      int ad = (lr >> 1) * 1040 + (lr & 1) * 512 + ks * 128 + lg * 32;
      float4 a0 = *(const float4*)(Ab + ad);
      float4 a1 = *(const float4*)(Ab + ad + 16);
      rs += a0.x + a0.y + a0.z + a0.w + a1.x + a1.y + a1.z + a1.w;
      af[ks] = pack8(a0, a1);
    }
    rs += __shfl_xor(rs, 16);
    rs += __shfl_xor(rs, 32);           // full fp32 row sum of neighbor (s&3)*16+lr
    unsigned mask16 = (unsigned)(__ballot(rs == 0.0f) & 0xFFFFull);

    // 3. two passes of 4 N-tiles (acc live-range 16 regs)
    #pragma unroll 1
    for (int p = 0; p < 2; ++p) {
      f32x4 acc[4];
      #pragma unroll
      for (int tt = 0; tt < 4; ++tt) acc[tt] = (f32x4){0.f, 0.f, 0.f, 0.f};

      #pragma unroll
      for (int tt = 0; tt < 4; ++tt) {
        #pragma unroll
        for (int ks = 0; ks < 4; ++ks) {
          int jr = (p * 4 + tt) * 16 + lr;
          int d0 = ks * 32 + lg * 8;
          bf16x8 bf = *(const bf16x8*)((const char*)Wl + jr * 256 + ((d0 * 2) ^ ((jr & 7) << 4)));
          acc[tt] = __builtin_amdgcn_mfma_f32_16x16x32_bf16(af[ks], bf, acc[tt], 0, 0, 0);
        }
      }

      // relu + bias + mask, fold into running per-lane max
      #pragma unroll
      for (int tt = 0; tt < 4; ++tt) {
        #pragma unroll
        for (int r = 0; r < 4; ++r) {
          int row = lg * 4 + r;          // D-layout: row = (l>>4)*4 + reg
          float v = fmaxf(acc[tt][r] + bml[p * 4 + tt], 0.f);
          if ((mask16 >> row) & 1u) v = 0.f;
          pmax[p * 4 + tt] = fmaxf(pmax[p * 4 + tt], v);
        }
      }
    }

    // 4. row complete every 4 steps: fold + store (wave-private, no barrier)
    if ((s & 3) == 3) {
      #pragma unroll
      for (int t = 0; t < 8; ++t) {
        pmax[t] = fmaxf(pmax[t], __shfl_xor(pmax[t], 16));
        pmax[t] = fmaxf(pmax[t], __shfl_xor(pmax[t], 32));
      }
      if (l < 16) {
        #pragma unroll
        for (int t = 0; t < 8; ++t) pscr[w][t * 16 + l] = pmax[t];
      }
      // same-wave LDS write->read: compiler orders via lgkmcnt
      float2 pv = *(const float2*)&pscr[w][2 * l];
      __hip_bfloat162 h2 = __float22bfloat162_rn(pv);
      ((unsigned*)(pooled + (size_t)(brow0 + (s >> 2)) * D_HID))[l] = *(unsigned*)&h2;
      #pragma unroll
      for (int t = 0; t < 8; ++t) pmax[t] = 0.f;
    }
  }
}

// Kernel 2: out[b][j] = relu([input|pooled][b,:]·W_comb[j,:] + b_comb[j])
// Block = 64 rows x 64 cols (quarter of output cols), K = 256.  (R8 verbatim)
__global__ __launch_bounds__(256, 2)
void k2_comb(const float* __restrict__ inp, const unsigned short* __restrict__ pooled,
             const float* __restrict__ Wcomb, const float* __restrict__ bcomb,
             float* __restrict__ out) {
  __shared__ unsigned short Wl[64 * 256];  // 32KB: 64 output cols x K=256, row = 512B, swizzled

  const int tid = threadIdx.x;
  const int l = tid & 63;
  const int w = tid >> 6;
  const int mchunk = blockIdx.x >> 2;   // 64-row chunk, 0..63
  const int colq   = blockIdx.x & 3;    // 64-col quarter
  const int lr = l & 15;
  const int lg = l >> 4;

  const int row = mchunk * 64 + w * 16 + lr;

  // 0. issue A loads first — overlap with W staging
  float4 a0[4], a1[4];
  #pragma unroll
  for (int ks = 0; ks < 4; ++ks) {   // k < 128: fp32 input
    const float* p = inp + (size_t)row * 128 + ks * 32 + lg * 8;
    a0[ks] = *(const float4*)p;
    a1[ks] = *(const float4*)(p + 4);
  }
  bf16x8 af[8];
  #pragma unroll
  for (int ks = 4; ks < 8; ++ks) {   // k >= 128: pooled already bf16
    af[ks] = *(const bf16x8*)(pooled + (size_t)row * 128 + (ks - 4) * 32 + lg * 8);
  }

  // 1. stage W quarter -> LDS bf16 (swizzled)
  const float4* W4 = (const float4*)Wcomb;
  #pragma unroll
  for (int it = 0; it < 8; ++it) {
    int c  = it * 256 + tid;            // 8-float chunk, 0..2047
    int jr = c >> 5;                    // 0..63
    int d0 = (c & 31) * 8;
    int gidx = ((colq * 64 + jr) * 256 + d0) >> 2;  // float4 index into W_comb
    float4 a = W4[gidx];
    float4 bb = W4[gidx + 1];
    int byte = jr * 512 + ((d0 * 2) ^ ((jr & 7) << 4));
    *(bf16x8*)((char*)Wl + byte) = pack8(a, bb);
  }

  float bcl[4];
  #pragma unroll
  for (int t = 0; t < 4; ++t) bcl[t] = bcomb[colq * 64 + t * 16 + lr];

  #pragma unroll
  for (int ks = 0; ks < 4; ++ks) af[ks] = pack8(a0[ks], a1[ks]);

  __syncthreads();

  f32x4 acc[4];
  #pragma unroll
  for (int t = 0; t < 4; ++t) acc[t] = (f32x4){0.f, 0.f, 0.f, 0.f};
  #pragma unroll
  for (int t = 0; t < 4; ++t) {
    #pragma unroll
    for (int ks = 0; ks < 8; ++ks) {
      int jr = t * 16 + lr;
      int d0 = ks * 32 + lg * 8;
      bf16x8 bf = *(const bf16x8*)((const char*)Wl + jr * 512 + ((d0 * 2) ^ ((jr & 7) << 4)));
      acc[t] = __builtin_amdgcn_mfma_f32_16x16x32_bf16(af[ks], bf, acc[t], 0, 0, 0);
    }
  }

  #pragma unroll
  for (int t = 0; t < 4; ++t) {
    #pragma unroll
    for (int r = 0; r < 4; ++r) {
      int ro = mchunk * 64 + w * 16 + lg * 4 + r;
      int co = colq * 64 + t * 16 + lr;
      float v = acc[t][r] + bcl[t];
      out[(size_t)ro * 256 + co] = fmaxf(v, 0.f);
    }
  }
}

extern "C" void kernel_launch(void* const* d_in, const int* in_sizes, int n_in,
                              void* d_out, int out_size, void* d_ws, size_t ws_size,
                              hipStream_t stream) {
  const float* inp   = (const float*)d_in[0];
  const float* neigh = (const float*)d_in[1];
  const float* Wmlp  = (const float*)d_in[2];
  const float* bmlp  = (const float*)d_in[3];
  const float* Wcomb = (const float*)d_in[4];
  const float* bcomb = (const float*)d_in[5];
  float* out = (float*)d_out;
  unsigned short* pooled = (unsigned short*)d_ws;  // [4096][128] bf16, 1 MB

  k1_pool<<<256, 256, 0, stream>>>(neigh, Wmlp, bmlp, pooled);
  k2_comb<<<256, 256, 0, stream>>>(inp, pooled, Wcomb, bcomb, out);
}